// Round 5
// baseline (898.508 us; speedup 1.0000x reference)
//
#include <hip/hip_runtime.h>
#include <cstdint>
#include <cstddef>

// Problem constants: B=2, S=2048, D=1024, H=16, hd=64
constexpr int S_ = 2048;
constexpr int D_ = 1024;

typedef __attribute__((ext_vector_type(8))) short bf16x8;
typedef __attribute__((ext_vector_type(4))) float f32x4;

typedef __attribute__((address_space(1))) const unsigned int as1_uint;
typedef __attribute__((address_space(3))) unsigned int as3_uint;
#define ASYNC_CP16(g, l) \
  __builtin_amdgcn_global_load_lds((as1_uint*)(g), (as3_uint*)(l), 16, 0, 0)

__device__ __forceinline__ unsigned short f2b(float f) {
  unsigned int u = __float_as_uint(f);
  u += 0x7fffu + ((u >> 16) & 1u);
  return (unsigned short)(u >> 16);
}

// pack two floats to bf16 pair -> dword (low = a)
__device__ __forceinline__ unsigned int pk2(float a, float b) {
  unsigned int ua = __float_as_uint(a) + 0x8000u;
  unsigned int ub = __float_as_uint(b) + 0x8000u;
  return __builtin_amdgcn_perm(ub, ua, 0x07060302u);
}

// Fused prep: x->bf16 (blocks 0..4095), W4->bf16 cat (4096..8191), bias cat (8192)
__global__ void prep(const float* __restrict__ x,
                     const float* __restrict__ w0, const float* __restrict__ w1,
                     const float* __restrict__ w2, const float* __restrict__ w3,
                     const float* __restrict__ b0, const float* __restrict__ b1,
                     const float* __restrict__ b2,
                     unsigned short* __restrict__ xb,
                     unsigned short* __restrict__ wcat,
                     float* __restrict__ bcat) {
  int blk = blockIdx.x;
  if (blk < 4096) {
    int i = (blk * 256 + threadIdx.x) * 4;
    float4 v = *reinterpret_cast<const float4*>(x + i);
    ushort4 o;
    o.x = f2b(v.x); o.y = f2b(v.y); o.z = f2b(v.z); o.w = f2b(v.w);
    *reinterpret_cast<ushort4*>(xb + i) = o;
  } else if (blk < 8192) {
    int i = ((blk - 4096) * 256 + threadIdx.x) * 4;
    int which = i >> 20;
    const float* s = (which == 0) ? w0 : (which == 1) ? w1 : (which == 2) ? w2 : w3;
    float4 v = *reinterpret_cast<const float4*>(s + (i & 1048575));
    ushort4 o;
    o.x = f2b(v.x); o.y = f2b(v.y); o.z = f2b(v.z); o.w = f2b(v.w);
    *reinterpret_cast<ushort4*>(wcat + i) = o;
  } else {
#pragma unroll
    for (int k = 0; k < 12; ++k) {
      int idx = k * 256 + threadIdx.x;
      const float* s = (idx < 1024) ? b0 : (idx < 2048) ? b1 : b2;
      bcat[idx] = s[idx & 1023];
    }
  }
}

// C[m][n] = sum_k A[m][k]*Bm[n][k] + bias[n].  K=1024, M=4096.
// MODE 0: fp32 out [4096,1024] (proj), out2 unused.
// MODE 1: QKV scatter: Q,K bf16 [bh][s][d] into out (Q at 0, K at +4194304);
//         V written TRANSPOSED bf16 [bh][d][s] into out2.
template <int MODE>
__global__ __launch_bounds__(256) void gemm_bt(
    const unsigned short* __restrict__ A,
    const unsigned short* __restrict__ Bm,
    const float* __restrict__ bias,
    void* __restrict__ out, void* __restrict__ out2) {
  constexpr int K = 1024;
  __shared__ __align__(16) unsigned short sA[128 * 64];
  __shared__ __align__(16) unsigned short sB[128 * 64];
  const int tid = threadIdx.x;
  const int w = tid >> 6, lane = tid & 63;
  const int l15 = lane & 15, quad = lane >> 4, l7 = lane & 7;
  const int m0 = blockIdx.y * 128, n0 = blockIdx.x * 128;
  const int wm = (w >> 1) * 64, wn = (w & 1) * 64;

  const int lr = lane >> 3;
  const int lc = l7 ^ lr;
  const unsigned short* ga = A + (size_t)(m0 + w * 32 + lr) * K + lc * 8;
  const unsigned short* gb = Bm + (size_t)(n0 + w * 32 + lr) * K + lc * 8;
  unsigned short* la = sA + w * 32 * 64;
  unsigned short* lb = sB + w * 32 * 64;

  f32x4 acc[4][4] = {};

  for (int kt = 0; kt < K; kt += 64) {
    __syncthreads();
#pragma unroll
    for (int c = 0; c < 4; ++c) {
      ASYNC_CP16(ga + c * 8 * K + kt, la + c * 8 * 64);
      ASYNC_CP16(gb + c * 8 * K + kt, lb + c * 8 * 64);
    }
    __syncthreads();
#pragma unroll
    for (int s = 0; s < 2; ++s) {
      bf16x8 af[4], bfr[4];
#pragma unroll
      for (int mt = 0; mt < 4; ++mt)
        af[mt] = *reinterpret_cast<const bf16x8*>(
            sA + (wm + mt * 16 + l15) * 64 + ((s * 4 + quad) ^ (l15 & 7)) * 8);
#pragma unroll
      for (int nt = 0; nt < 4; ++nt)
        bfr[nt] = *reinterpret_cast<const bf16x8*>(
            sB + (wn + nt * 16 + l15) * 64 + ((s * 4 + quad) ^ (l15 & 7)) * 8);
#pragma unroll
      for (int mt = 0; mt < 4; ++mt)
#pragma unroll
        for (int nt = 0; nt < 4; ++nt)
          acc[mt][nt] = __builtin_amdgcn_mfma_f32_16x16x32_bf16(af[mt], bfr[nt], acc[mt][nt], 0, 0, 0);
    }
  }

#pragma unroll
  for (int mt = 0; mt < 4; ++mt) {
#pragma unroll
    for (int nt = 0; nt < 4; ++nt) {
      int col = n0 + wn + nt * 16 + l15;
      float bv = bias[col];
      int row0 = m0 + wm + mt * 16 + quad * 4;
      float v0 = acc[mt][nt][0] + bv, v1 = acc[mt][nt][1] + bv;
      float v2 = acc[mt][nt][2] + bv, v3 = acc[mt][nt][3] + bv;
      if (MODE == 0) {
        float* op = (float*)out;
        op[(size_t)(row0 + 0) * 1024 + col] = v0;
        op[(size_t)(row0 + 1) * 1024 + col] = v1;
        op[(size_t)(row0 + 2) * 1024 + col] = v2;
        op[(size_t)(row0 + 3) * 1024 + col] = v3;
      } else {
        int which = col >> 10, rem = col & 1023;
        int h = rem >> 6, d = rem & 63;
        int b = row0 >> 11, s0 = row0 & 2047;
        int bh = b * 16 + h;
        if (which == 2) {
          uint2 pv;
          pv.x = pk2(v0, v1);
          pv.y = pk2(v2, v3);
          *reinterpret_cast<uint2*>((unsigned short*)out2 +
                                    ((size_t)bh * 64 + d) * 2048 + s0) = pv;
        } else {
          unsigned short* op = (unsigned short*)out + (size_t)which * 4194304 +
                               (((size_t)bh * 2048 + s0) * 64 + d);
          op[0 * 64] = f2b(v0);
          op[1 * 64] = f2b(v1);
          op[2 * 64] = f2b(v2);
          op[3 * 64] = f2b(v3);
        }
      }
    }
  }
}

// Flash attention, S^T formulation, fixed-max softmax (shift-invariant).
// Q,K: [bh][s][64] bf16; Vt: [bh][d][s] bf16; mask int32 [bh][q][k]; ctx bf16 [B][s][D].
__global__ __launch_bounds__(256) void attn_kernel(
    const unsigned short* __restrict__ Q,
    const unsigned short* __restrict__ K,
    const unsigned short* __restrict__ Vt,
    const int* __restrict__ mask,
    unsigned short* __restrict__ ctx) {
  constexpr int LDP = 136;
  __shared__ __align__(16) unsigned short sK[128 * 64];
  __shared__ __align__(16) unsigned short sVT[64 * 128];
  __shared__ __align__(16) unsigned short sP[4 * 16 * LDP];
  const int tid = threadIdx.x;
  const int w = tid >> 6, lane = tid & 63;
  const int l15 = lane & 15, quad = lane >> 4, l7 = lane & 7;
  const int bh = blockIdx.y;
  const int b = bh >> 4, h = bh & 15;
  const unsigned short* Qp = Q + (size_t)bh * S_ * 64;
  const unsigned short* Kp = K + (size_t)bh * S_ * 64;
  const unsigned short* Vp = Vt + (size_t)bh * 64 * S_;
  const int* mp = mask + (size_t)bh * S_ * S_;
  const int qw = blockIdx.x * 64 + w * 16;

  bf16x8 aq[2];
  aq[0] = *reinterpret_cast<const bf16x8*>(Qp + (size_t)(qw + l15) * 64 + quad * 8);
  aq[1] = *reinterpret_cast<const bf16x8*>(Qp + (size_t)(qw + l15) * 64 + 32 + quad * 8);

  float l_run = 0.f;
  f32x4 o[4] = {};

  const int lr = lane >> 3;
  const int lcK = l7 ^ lr;
  const unsigned short* gk = Kp + (size_t)(w * 32 + lr) * 64 + lcK * 8;
  unsigned short* lk = sK + w * 32 * 64;
  const int vrow_base = w * 16 + quad;
  unsigned short* sPw = sP + w * 16 * LDP;

  // exp(0.125*s - 8) == exp2(0.1803369*s - 11.54156)
  constexpr float C1 = 0.18033688011112042f;
  constexpr float C0 = -11.541560327111707f;

  for (int kt = 0; kt < S_; kt += 128) {
    __syncthreads();
#pragma unroll
    for (int c = 0; c < 4; ++c)
      ASYNC_CP16(gk + (size_t)(kt + c * 8) * 64, lk + c * 8 * 64);
#pragma unroll
    for (int c = 0; c < 4; ++c) {
      int vrow = vrow_base + c * 4;
      ASYNC_CP16(Vp + (size_t)vrow * S_ + kt + ((l15 ^ (vrow & 7)) * 8),
                 sVT + (w * 16 + c * 4) * 128);
    }
    __syncthreads();

#pragma unroll
    for (int nt = 0; nt < 8; ++nt) {
      f32x4 sacc = {0.f, 0.f, 0.f, 0.f};
#pragma unroll
      for (int s = 0; s < 2; ++s) {
        bf16x8 ak = *reinterpret_cast<const bf16x8*>(
            sK + (nt * 16 + l15) * 64 + ((s * 4 + quad) ^ (l15 & 7)) * 8);
        sacc = __builtin_amdgcn_mfma_f32_16x16x32_bf16(ak, aq[s], sacc, 0, 0, 0);
      }
      const int4 mv = *reinterpret_cast<const int4*>(
          mp + (size_t)(qw + l15) * S_ + kt + nt * 16 + quad * 4);
      float p0 = mv.x ? exp2f(fmaf(sacc[0], C1, C0)) : 0.f;
      float p1 = mv.y ? exp2f(fmaf(sacc[1], C1, C0)) : 0.f;
      float p2 = mv.z ? exp2f(fmaf(sacc[2], C1, C0)) : 0.f;
      float p3 = mv.w ? exp2f(fmaf(sacc[3], C1, C0)) : 0.f;
      l_run += (p0 + p1) + (p2 + p3);
      uint2 pw;
      pw.x = pk2(p0, p1);
      pw.y = pk2(p2, p3);
      *reinterpret_cast<uint2*>(sPw + l15 * LDP + nt * 16 + quad * 4) = pw;
    }

#pragma unroll
    for (int c = 0; c < 4; ++c) {
      bf16x8 bp = *reinterpret_cast<const bf16x8*>(sPw + l15 * LDP + c * 32 + quad * 8);
#pragma unroll
      for (int dt = 0; dt < 4; ++dt) {
        bf16x8 av = *reinterpret_cast<const bf16x8*>(
            sVT + (dt * 16 + l15) * 128 + (((c * 4 + quad) ^ (l15 & 7)) * 8));
        o[dt] = __builtin_amdgcn_mfma_f32_16x16x32_bf16(av, bp, o[dt], 0, 0, 0);
      }
    }
  }

  l_run += __shfl_xor(l_run, 16, 64);
  l_run += __shfl_xor(l_run, 32, 64);
  float invl = (l_run > 0.f) ? (1.0f / l_run) : 0.f;

  unsigned short* cp = ctx + ((size_t)(b * 2048 + qw + l15)) * 1024 + h * 64 + quad * 4;
#pragma unroll
  for (int dt = 0; dt < 4; ++dt) {
    uint2 ov;
    ov.x = pk2(o[dt][0] * invl, o[dt][1] * invl);
    ov.y = pk2(o[dt][2] * invl, o[dt][3] * invl);
    *reinterpret_cast<uint2*>(cp + dt * 16) = ov;
  }
}

extern "C" void kernel_launch(void* const* d_in, const int* in_sizes, int n_in,
                              void* d_out, int out_size, void* d_ws, size_t ws_size,
                              hipStream_t stream) {
  const float* x    = (const float*)d_in[0];
  const int*   mask = (const int*)d_in[1];
  const float* Wq   = (const float*)d_in[2];
  const float* bq   = (const float*)d_in[3];
  const float* Wk   = (const float*)d_in[4];
  const float* bk   = (const float*)d_in[5];
  const float* Wv   = (const float*)d_in[6];
  const float* bv   = (const float*)d_in[7];
  const float* Wo   = (const float*)d_in[8];
  const float* bo   = (const float*)d_in[9];
  float* out = (float*)d_out;

  char* ws = (char*)d_ws;
  const size_t MB = 1048576;
  unsigned short* xb   = (unsigned short*)(ws);             // 8 MB
  unsigned short* Wcat = (unsigned short*)(ws + 8 * MB);    // 8 MB [Wq|Wk|Wv|Wo]
  unsigned short* Qw   = (unsigned short*)(ws + 16 * MB);   // Q 8MB, K 8MB
  unsigned short* Vt   = (unsigned short*)(ws + 32 * MB);   // V transposed 8MB
  unsigned short* Cw   = (unsigned short*)(ws + 40 * MB);   // ctx bf16 8MB
  float*          bcat = (float*)(ws + 48 * MB);            // 12 KB

  unsigned short* Kw = Qw + 4194304;

  prep<<<8193, 256, 0, stream>>>(x, Wq, Wk, Wv, Wo, bq, bk, bv, xb, Wcat, bcat);
  gemm_bt<1><<<dim3(24, 32), 256, 0, stream>>>(xb, Wcat, bcat, Qw, Vt);
  attn_kernel<<<dim3(32, 32), 256, 0, stream>>>(Qw, Kw, Vt, mask, Cw);
  gemm_bt<0><<<dim3(8, 32), 256, 0, stream>>>(Cw, Wcat + 3 * 1048576, bo, out, nullptr);
}

// Round 6
// 808.429 us; speedup vs baseline: 1.1114x; 1.1114x over previous
//
#include <hip/hip_runtime.h>
#include <cstdint>
#include <cstddef>

// Problem constants: B=2, S=2048, D=1024, H=16, hd=64
constexpr int S_ = 2048;
constexpr int D_ = 1024;

typedef __attribute__((ext_vector_type(8))) short bf16x8;
typedef __attribute__((ext_vector_type(4))) float f32x4;

typedef __attribute__((address_space(1))) const unsigned int as1_uint;
typedef __attribute__((address_space(3))) unsigned int as3_uint;
#define ASYNC_CP16(g, l) \
  __builtin_amdgcn_global_load_lds((as1_uint*)(g), (as3_uint*)(l), 16, 0, 0)

__device__ __forceinline__ unsigned short f2b(float f) {
  unsigned int u = __float_as_uint(f);
  u += 0x7fffu + ((u >> 16) & 1u);
  return (unsigned short)(u >> 16);
}

// pack two floats to bf16 pair -> dword (low = a)
__device__ __forceinline__ unsigned int pk2(float a, float b) {
  unsigned int ua = __float_as_uint(a) + 0x8000u;
  unsigned int ub = __float_as_uint(b) + 0x8000u;
  return __builtin_amdgcn_perm(ub, ua, 0x07060302u);
}

// Fused prep: x->bf16 (blocks 0..4095), W4->bf16 cat (4096..8191), bias cat (8192)
__global__ void prep(const float* __restrict__ x,
                     const float* __restrict__ w0, const float* __restrict__ w1,
                     const float* __restrict__ w2, const float* __restrict__ w3,
                     const float* __restrict__ b0, const float* __restrict__ b1,
                     const float* __restrict__ b2,
                     unsigned short* __restrict__ xb,
                     unsigned short* __restrict__ wcat,
                     float* __restrict__ bcat) {
  int blk = blockIdx.x;
  if (blk < 4096) {
    int i = (blk * 256 + threadIdx.x) * 4;
    float4 v = *reinterpret_cast<const float4*>(x + i);
    ushort4 o;
    o.x = f2b(v.x); o.y = f2b(v.y); o.z = f2b(v.z); o.w = f2b(v.w);
    *reinterpret_cast<ushort4*>(xb + i) = o;
  } else if (blk < 8192) {
    int i = ((blk - 4096) * 256 + threadIdx.x) * 4;
    int which = i >> 20;
    const float* s = (which == 0) ? w0 : (which == 1) ? w1 : (which == 2) ? w2 : w3;
    float4 v = *reinterpret_cast<const float4*>(s + (i & 1048575));
    ushort4 o;
    o.x = f2b(v.x); o.y = f2b(v.y); o.z = f2b(v.z); o.w = f2b(v.w);
    *reinterpret_cast<ushort4*>(wcat + i) = o;
  } else {
#pragma unroll
    for (int k = 0; k < 12; ++k) {
      int idx = k * 256 + threadIdx.x;
      const float* s = (idx < 1024) ? b0 : (idx < 2048) ? b1 : b2;
      bcat[idx] = s[idx & 1023];
    }
  }
}

// C[m][n] = sum_k A[m][k]*Bm[n][k] + bias[n].  K=1024, M=4096.
// MODE 0: fp32 out [4096,1024] (proj), out2 unused.
// MODE 1: QKV scatter: Q,K bf16 [bh][s][d] into out (Q at 0, K at +4194304);
//         V written TRANSPOSED bf16 [bh][d][s] into out2.
template <int MODE>
__global__ __launch_bounds__(256) void gemm_bt(
    const unsigned short* __restrict__ A,
    const unsigned short* __restrict__ Bm,
    const float* __restrict__ bias,
    void* __restrict__ out, void* __restrict__ out2) {
  constexpr int K = 1024;
  __shared__ __align__(16) unsigned short sA[128 * 64];
  __shared__ __align__(16) unsigned short sB[128 * 64];
  const int tid = threadIdx.x;
  const int w = tid >> 6, lane = tid & 63;
  const int l15 = lane & 15, quad = lane >> 4, l7 = lane & 7;
  const int m0 = blockIdx.y * 128, n0 = blockIdx.x * 128;
  const int wm = (w >> 1) * 64, wn = (w & 1) * 64;

  const int lr = lane >> 3;
  const int lc = l7 ^ lr;
  const unsigned short* ga = A + (size_t)(m0 + w * 32 + lr) * K + lc * 8;
  const unsigned short* gb = Bm + (size_t)(n0 + w * 32 + lr) * K + lc * 8;
  unsigned short* la = sA + w * 32 * 64;
  unsigned short* lb = sB + w * 32 * 64;

  f32x4 acc[4][4] = {};

  for (int kt = 0; kt < K; kt += 64) {
    __syncthreads();
#pragma unroll
    for (int c = 0; c < 4; ++c) {
      ASYNC_CP16(ga + c * 8 * K + kt, la + c * 8 * 64);
      ASYNC_CP16(gb + c * 8 * K + kt, lb + c * 8 * 64);
    }
    __syncthreads();
#pragma unroll
    for (int s = 0; s < 2; ++s) {
      bf16x8 af[4], bfr[4];
#pragma unroll
      for (int mt = 0; mt < 4; ++mt)
        af[mt] = *reinterpret_cast<const bf16x8*>(
            sA + (wm + mt * 16 + l15) * 64 + ((s * 4 + quad) ^ (l15 & 7)) * 8);
#pragma unroll
      for (int nt = 0; nt < 4; ++nt)
        bfr[nt] = *reinterpret_cast<const bf16x8*>(
            sB + (wn + nt * 16 + l15) * 64 + ((s * 4 + quad) ^ (l15 & 7)) * 8);
#pragma unroll
      for (int mt = 0; mt < 4; ++mt)
#pragma unroll
        for (int nt = 0; nt < 4; ++nt)
          acc[mt][nt] = __builtin_amdgcn_mfma_f32_16x16x32_bf16(af[mt], bfr[nt], acc[mt][nt], 0, 0, 0);
    }
  }

#pragma unroll
  for (int mt = 0; mt < 4; ++mt) {
#pragma unroll
    for (int nt = 0; nt < 4; ++nt) {
      int col = n0 + wn + nt * 16 + l15;
      float bv = bias[col];
      int row0 = m0 + wm + mt * 16 + quad * 4;
      float v0 = acc[mt][nt][0] + bv, v1 = acc[mt][nt][1] + bv;
      float v2 = acc[mt][nt][2] + bv, v3 = acc[mt][nt][3] + bv;
      if (MODE == 0) {
        float* op = (float*)out;
        op[(size_t)(row0 + 0) * 1024 + col] = v0;
        op[(size_t)(row0 + 1) * 1024 + col] = v1;
        op[(size_t)(row0 + 2) * 1024 + col] = v2;
        op[(size_t)(row0 + 3) * 1024 + col] = v3;
      } else {
        int which = col >> 10, rem = col & 1023;
        int h = rem >> 6, d = rem & 63;
        int b = row0 >> 11, s0 = row0 & 2047;
        int bh = b * 16 + h;
        if (which == 2) {
          uint2 pv;
          pv.x = pk2(v0, v1);
          pv.y = pk2(v2, v3);
          *reinterpret_cast<uint2*>((unsigned short*)out2 +
                                    ((size_t)bh * 64 + d) * 2048 + s0) = pv;
        } else {
          unsigned short* op = (unsigned short*)out + (size_t)which * 4194304 +
                               (((size_t)bh * 2048 + s0) * 64 + d);
          op[0 * 64] = f2b(v0);
          op[1 * 64] = f2b(v1);
          op[2 * 64] = f2b(v2);
          op[3 * 64] = f2b(v3);
        }
      }
    }
  }
}

// Flash attention, S^T formulation, fixed-max softmax (shift-invariant).
// Q,K: [bh][s][64] bf16; Vt: [bh][d][s] bf16; mask int32 [bh][q][k]; ctx bf16 [B][s][D].
// Mask stream is software-pipelined: tile t+1's 8 int4 loads issue before tile t's
// compute, giving a full K-tile of latency cover for the only HBM stream in the loop.
__global__ __launch_bounds__(256) void attn_kernel(
    const unsigned short* __restrict__ Q,
    const unsigned short* __restrict__ K,
    const unsigned short* __restrict__ Vt,
    const int* __restrict__ mask,
    unsigned short* __restrict__ ctx) {
  constexpr int LDP = 136;
  __shared__ __align__(16) unsigned short sK[128 * 64];
  __shared__ __align__(16) unsigned short sVT[64 * 128];
  __shared__ __align__(16) unsigned short sP[4 * 16 * LDP];
  const int tid = threadIdx.x;
  const int w = tid >> 6, lane = tid & 63;
  const int l15 = lane & 15, quad = lane >> 4, l7 = lane & 7;
  const int bh = blockIdx.y;
  const int b = bh >> 4, h = bh & 15;
  const unsigned short* Qp = Q + (size_t)bh * S_ * 64;
  const unsigned short* Kp = K + (size_t)bh * S_ * 64;
  const unsigned short* Vp = Vt + (size_t)bh * 64 * S_;
  const int* mp = mask + (size_t)bh * S_ * S_;
  const int qw = blockIdx.x * 64 + w * 16;

  bf16x8 aq[2];
  aq[0] = *reinterpret_cast<const bf16x8*>(Qp + (size_t)(qw + l15) * 64 + quad * 8);
  aq[1] = *reinterpret_cast<const bf16x8*>(Qp + (size_t)(qw + l15) * 64 + 32 + quad * 8);

  float l_run = 0.f;
  f32x4 o[4] = {};

  const int lr = lane >> 3;
  const int lcK = l7 ^ lr;
  const unsigned short* gk = Kp + (size_t)(w * 32 + lr) * 64 + lcK * 8;
  unsigned short* lk = sK + w * 32 * 64;
  const int vrow_base = w * 16 + quad;
  unsigned short* sPw = sP + w * 16 * LDP;

  // exp(0.125*s - 8) == exp2(0.1803369*s - 11.54156)
  constexpr float C1 = 0.18033688011112042f;
  constexpr float C0 = -11.541560327111707f;

  // this lane's mask row/phase: mask[q = qw+l15][k = kt + nt*16 + quad*4 + 0..3]
  const int* mrow = mp + (size_t)(qw + l15) * S_ + quad * 4;

  // prefetch mask tile 0
  int4 mv[8];
#pragma unroll
  for (int nt = 0; nt < 8; ++nt)
    mv[nt] = *reinterpret_cast<const int4*>(mrow + nt * 16);

  for (int kt = 0; kt < S_; kt += 128) {
    __syncthreads();
#pragma unroll
    for (int c = 0; c < 4; ++c)
      ASYNC_CP16(gk + (size_t)(kt + c * 8) * 64, lk + c * 8 * 64);
#pragma unroll
    for (int c = 0; c < 4; ++c) {
      int vrow = vrow_base + c * 4;
      ASYNC_CP16(Vp + (size_t)vrow * S_ + kt + ((l15 ^ (vrow & 7)) * 8),
                 sVT + (w * 16 + c * 4) * 128);
    }
    __syncthreads();

    // issue next tile's mask loads now (consumed next iteration)
    const int ktn = (kt + 128 < S_) ? (kt + 128) : kt;  // wave-uniform clamp
    int4 mvn[8];
#pragma unroll
    for (int nt = 0; nt < 8; ++nt)
      mvn[nt] = *reinterpret_cast<const int4*>(mrow + ktn + nt * 16);

#pragma unroll
    for (int nt = 0; nt < 8; ++nt) {
      f32x4 sacc = {0.f, 0.f, 0.f, 0.f};
#pragma unroll
      for (int s = 0; s < 2; ++s) {
        bf16x8 ak = *reinterpret_cast<const bf16x8*>(
            sK + (nt * 16 + l15) * 64 + ((s * 4 + quad) ^ (l15 & 7)) * 8);
        sacc = __builtin_amdgcn_mfma_f32_16x16x32_bf16(ak, aq[s], sacc, 0, 0, 0);
      }
      float p0 = mv[nt].x ? exp2f(fmaf(sacc[0], C1, C0)) : 0.f;
      float p1 = mv[nt].y ? exp2f(fmaf(sacc[1], C1, C0)) : 0.f;
      float p2 = mv[nt].z ? exp2f(fmaf(sacc[2], C1, C0)) : 0.f;
      float p3 = mv[nt].w ? exp2f(fmaf(sacc[3], C1, C0)) : 0.f;
      l_run += (p0 + p1) + (p2 + p3);
      uint2 pw;
      pw.x = pk2(p0, p1);
      pw.y = pk2(p2, p3);
      *reinterpret_cast<uint2*>(sPw + l15 * LDP + nt * 16 + quad * 4) = pw;
    }

#pragma unroll
    for (int c = 0; c < 4; ++c) {
      bf16x8 bp = *reinterpret_cast<const bf16x8*>(sPw + l15 * LDP + c * 32 + quad * 8);
#pragma unroll
      for (int dt = 0; dt < 4; ++dt) {
        bf16x8 av = *reinterpret_cast<const bf16x8*>(
            sVT + (dt * 16 + l15) * 128 + (((c * 4 + quad) ^ (l15 & 7)) * 8));
        o[dt] = __builtin_amdgcn_mfma_f32_16x16x32_bf16(av, bp, o[dt], 0, 0, 0);
      }
    }

#pragma unroll
    for (int nt = 0; nt < 8; ++nt) mv[nt] = mvn[nt];
  }

  l_run += __shfl_xor(l_run, 16, 64);
  l_run += __shfl_xor(l_run, 32, 64);
  float invl = (l_run > 0.f) ? (1.0f / l_run) : 0.f;

  unsigned short* cp = ctx + ((size_t)(b * 2048 + qw + l15)) * 1024 + h * 64 + quad * 4;
#pragma unroll
  for (int dt = 0; dt < 4; ++dt) {
    uint2 ov;
    ov.x = pk2(o[dt][0] * invl, o[dt][1] * invl);
    ov.y = pk2(o[dt][2] * invl, o[dt][3] * invl);
    *reinterpret_cast<uint2*>(cp + dt * 16) = ov;
  }
}

extern "C" void kernel_launch(void* const* d_in, const int* in_sizes, int n_in,
                              void* d_out, int out_size, void* d_ws, size_t ws_size,
                              hipStream_t stream) {
  const float* x    = (const float*)d_in[0];
  const int*   mask = (const int*)d_in[1];
  const float* Wq   = (const float*)d_in[2];
  const float* bq   = (const float*)d_in[3];
  const float* Wk   = (const float*)d_in[4];
  const float* bk   = (const float*)d_in[5];
  const float* Wv   = (const float*)d_in[6];
  const float* bv   = (const float*)d_in[7];
  const float* Wo   = (const float*)d_in[8];
  const float* bo   = (const float*)d_in[9];
  float* out = (float*)d_out;

  char* ws = (char*)d_ws;
  const size_t MB = 1048576;
  unsigned short* xb   = (unsigned short*)(ws);             // 8 MB
  unsigned short* Wcat = (unsigned short*)(ws + 8 * MB);    // 8 MB [Wq|Wk|Wv|Wo]
  unsigned short* Qw   = (unsigned short*)(ws + 16 * MB);   // Q 8MB, K 8MB
  unsigned short* Vt   = (unsigned short*)(ws + 32 * MB);   // V transposed 8MB
  unsigned short* Cw   = (unsigned short*)(ws + 40 * MB);   // ctx bf16 8MB
  float*          bcat = (float*)(ws + 48 * MB);            // 12 KB

  unsigned short* Kw = Qw + 4194304;

  prep<<<8193, 256, 0, stream>>>(x, Wq, Wk, Wv, Wo, bq, bk, bv, xb, Wcat, bcat);
  gemm_bt<1><<<dim3(24, 32), 256, 0, stream>>>(xb, Wcat, bcat, Qw, Vt);
  attn_kernel<<<dim3(32, 32), 256, 0, stream>>>(Qw, Kw, Vt, mask, Cw);
  gemm_bt<0><<<dim3(8, 32), 256, 0, stream>>>(Cw, Wcat + 3 * 1048576, bo, out, nullptr);
}